// Round 1
// 879.084 us; speedup vs baseline: 1.0130x; 1.0130x over previous
//
#include <hip/hip_runtime.h>

#define BLOCK 256
#define ROW_D 16384
#define VPT (ROW_D / (BLOCK * 4))  // 16 float4 per thread = 64 floats
#define NC 8                       // histogram copies (LDS bank spread)
#define CAP 4096                   // candidate slots (expected use ~400)

// Monotonic bijection: float order == unsigned order of key.
__device__ __forceinline__ unsigned keyOf(float f) {
    unsigned u = __float_as_uint(f);
    return (u & 0x80000000u) ? ~u : (u | 0x80000000u);
}
__device__ __forceinline__ float valOf(unsigned m) {
    unsigned u = (m & 0x80000000u) ? (m & 0x7FFFFFFFu) : ~m;
    return __uint_as_float(u);
}

// Wave 0 only (threads 0..63). S[256] holds per-bin counts. Finds the unique
// bin b with suffix(b) >= rank > suffix(b+1), suffix(b) = sum_{b'>=b} S[b'].
// Barrier-free: lane-local suffix over 4 bins + shfl_down suffix-scan.
__device__ __forceinline__ void waveFind(const unsigned* S, unsigned rank, int l,
                                         unsigned* dDigit, unsigned* dGreater,
                                         unsigned* dBinCnt) {
    uint4 h = *reinterpret_cast<const uint4*>(S + 4 * l);
    unsigned s3 = h.w;
    unsigned s2 = h.z + s3;
    unsigned s1 = h.y + s2;
    unsigned s0 = h.x + s1;
    unsigned inc = s0;
#pragma unroll
    for (int off = 1; off < 64; off <<= 1) {
        unsigned v = __shfl_down(inc, off);
        if (l + off < 64) inc += v;
    }
    const unsigned E = inc - s0;  // suffix of all bins after this lane's four
    const unsigned su0 = s0 + E, su1 = s1 + E, su2 = s2 + E, su3 = s3 + E, su4 = E;
    if (su0 >= rank && su1 < rank) { *dDigit = 4u * l + 0u; *dGreater = su1; *dBinCnt = su0 - su1; }
    if (su1 >= rank && su2 < rank) { *dDigit = 4u * l + 1u; *dGreater = su2; *dBinCnt = su1 - su2; }
    if (su2 >= rank && su3 < rank) { *dDigit = 4u * l + 2u; *dGreater = su3; *dBinCnt = su2 - su3; }
    if (su3 >= rank && su4 < rank) { *dDigit = 4u * l + 3u; *dGreater = su4; *dBinCnt = su3 - su4; }
}

__global__ __launch_bounds__(BLOCK, 4)
void TopKActivation_68324339745162_kernel(const float* __restrict__ in,
                                          float* __restrict__ out,
                                          const int* __restrict__ kptr) {
    __shared__ unsigned hist[256 * NC];        // 8 KiB
    __shared__ __align__(16) unsigned S[256];  // 1 KiB (uint4-read by wave 0)
    __shared__ unsigned cand[CAP];             // 16 KiB
    __shared__ unsigned sDigit, sGreater, sBinCnt, sCnt, sBase;

    const int t = threadIdx.x;
    const unsigned cpy = (unsigned)t & (NC - 1u);
    const size_t rowOff = (size_t)blockIdx.x * (size_t)ROW_D;
    const float4* inRow = reinterpret_cast<const float4*>(in + rowOff);
    float4* outRow = reinterpret_cast<float4*>(out + rowOff);

    // ---- Load row: keys in registers (64 VGPRs); fold per-thread max ----
    uint4 keys[VPT];
    unsigned mx = 0u;
#pragma unroll
    for (int j = 0; j < VPT; ++j) {
        float4 v = inRow[t + BLOCK * j];
        keys[j].x = keyOf(v.x);
        keys[j].y = keyOf(v.y);
        keys[j].z = keyOf(v.z);
        keys[j].w = keyOf(v.w);
        unsigned a = keys[j].x > keys[j].y ? keys[j].x : keys[j].y;
        unsigned b = keys[j].z > keys[j].w ? keys[j].z : keys[j].w;
        a = a > b ? a : b;
        mx = mx > a ? mx : a;
    }

    const unsigned k0 = (unsigned)(*kptr);
    // Screen validity needs k0 <= #thread-maxima (=BLOCK).
    const bool screenOK = (k0 >= 1u && k0 <= (unsigned)BLOCK);

    // ---- Phase 1: screen. Bin of the k-th largest THREAD-MAX: >= k0 maxima
    // (distinct elements) are >= that bin's floor L, so L <= true threshold;
    // "key >= L" provably keeps every top-k element (incl. all ties).
    for (int i = t; i < 256 * NC; i += BLOCK) hist[i] = 0u;
    if (t == 0) sCnt = 0u;
    __syncthreads();
    atomicAdd(&hist[((mx >> 24) << 3) | cpy], 1u);
    __syncthreads();
    {
        unsigned s = 0u;
#pragma unroll
        for (int c = 0; c < NC; ++c)
            s += hist[((unsigned)t << 3) | (((unsigned)t + (unsigned)c) & (NC - 1u))];
        S[t] = s;
    }
    __syncthreads();
    if (t < 64) waveFind(S, screenOK ? k0 : 256u, t, &sDigit, &sGreater, &sBinCnt);
    __syncthreads();
    const unsigned Lkey = sDigit << 24;

    // ---- Phase 2: compact candidates (key >= L) into LDS (~400 expected) ----
    if (screenOK) {
#pragma unroll
        for (int j = 0; j < VPT; ++j) {
            unsigned kk;
            kk = keys[j].x; if (kk >= Lkey) { unsigned p = atomicAdd(&sCnt, 1u); if (p < CAP) cand[p] = kk; }
            kk = keys[j].y; if (kk >= Lkey) { unsigned p = atomicAdd(&sCnt, 1u); if (p < CAP) cand[p] = kk; }
            kk = keys[j].z; if (kk >= Lkey) { unsigned p = atomicAdd(&sCnt, 1u); if (p < CAP) cand[p] = kk; }
            kk = keys[j].w; if (kk >= Lkey) { unsigned p = atomicAdd(&sCnt, 1u); if (p < CAP) cand[p] = kk; }
        }
    }
    __syncthreads();
    const unsigned M = sCnt;
    const bool useCand = screenOK && (M <= (unsigned)CAP);  // block-uniform

    // ---- Phase 3: 4x 8-bit radix select (MSB first) for the k-th largest.
    // Runs over the small candidate list; exact register-path fallback if the
    // buffer overflowed (degenerate/tied rows) or k0 > BLOCK.
    unsigned rank = k0, prefix = 0u, pmask = 0u;
    for (int pass = 0; pass < 4; ++pass) {
        const int shift = 24 - 8 * pass;
        for (int i = t; i < 256 * NC; i += BLOCK) hist[i] = 0u;
        __syncthreads();
        if (useCand) {
            for (unsigned i = (unsigned)t; i < M; i += BLOCK) {
                unsigned ck = cand[i];
                if ((ck & pmask) == prefix)
                    atomicAdd(&hist[(((ck >> shift) & 255u) << 3) | cpy], 1u);
            }
        } else {
#pragma unroll
            for (int j = 0; j < VPT; ++j) {
                unsigned kk;
                kk = keys[j].x; if ((kk & pmask) == prefix) atomicAdd(&hist[(((kk >> shift) & 255u) << 3) | cpy], 1u);
                kk = keys[j].y; if ((kk & pmask) == prefix) atomicAdd(&hist[(((kk >> shift) & 255u) << 3) | cpy], 1u);
                kk = keys[j].z; if ((kk & pmask) == prefix) atomicAdd(&hist[(((kk >> shift) & 255u) << 3) | cpy], 1u);
                kk = keys[j].w; if ((kk & pmask) == prefix) atomicAdd(&hist[(((kk >> shift) & 255u) << 3) | cpy], 1u);
            }
        }
        __syncthreads();
        {
            unsigned s = 0u;
#pragma unroll
            for (int c = 0; c < NC; ++c)
                s += hist[((unsigned)t << 3) | (((unsigned)t + (unsigned)c) & (NC - 1u))];
            S[t] = s;
        }
        __syncthreads();
        if (t < 64) waveFind(S, rank, t, &sDigit, &sGreater, &sBinCnt);
        __syncthreads();
        rank -= sGreater;
        prefix |= sDigit << shift;
        pmask |= 255u << shift;
    }

    const unsigned T = prefix;        // exact key of the k-th largest element
    const unsigned need = rank;       // how many ties (== T) to accept
    const bool fastTies = (sBinCnt == need);  // block-uniform

    if (fastTies) {
        // Common case: accept every element == T (usually exactly one).
#pragma unroll
        for (int j = 0; j < VPT; ++j) {
            float4 o;
            o.x = (keys[j].x >= T) ? valOf(keys[j].x) : 0.0f;
            o.y = (keys[j].y >= T) ? valOf(keys[j].y) : 0.0f;
            o.z = (keys[j].z >= T) ? valOf(keys[j].z) : 0.0f;
            o.w = (keys[j].w >= T) ? valOf(keys[j].w) : 0.0f;
            outRow[t + BLOCK * j] = o;
        }
    } else {
        // Cold path: duplicated threshold value — accept the `need` ties with
        // smallest global index (matches top_k's stable tie-break).
        // Element (j, t, c) has global index 1024*j + 4*t + c, so iterating
        // j-major with a per-j prefix scan over threads enumerates index order.
        if (t == 0) sBase = 0u;
        for (int j = 0; j < VPT; ++j) {
            unsigned lc = (unsigned)(keys[j].x == T) + (unsigned)(keys[j].y == T) +
                          (unsigned)(keys[j].z == T) + (unsigned)(keys[j].w == T);
            __syncthreads();
            S[t] = lc;
            __syncthreads();
            unsigned run = lc;
            for (int step = 1; step < 256; step <<= 1) {
                unsigned v = (t >= step) ? S[t - step] : 0u;
                __syncthreads();
                run += v;
                S[t] = run;
                __syncthreads();
            }
            unsigned r = run - lc + sBase;  // ties before my first element
            float4 o;
            {
                unsigned kk = keys[j].x;
                if (kk > T) o.x = valOf(kk);
                else if (kk == T) { o.x = (r < need) ? valOf(kk) : 0.0f; ++r; }
                else o.x = 0.0f;
            }
            {
                unsigned kk = keys[j].y;
                if (kk > T) o.y = valOf(kk);
                else if (kk == T) { o.y = (r < need) ? valOf(kk) : 0.0f; ++r; }
                else o.y = 0.0f;
            }
            {
                unsigned kk = keys[j].z;
                if (kk > T) o.z = valOf(kk);
                else if (kk == T) { o.z = (r < need) ? valOf(kk) : 0.0f; ++r; }
                else o.z = 0.0f;
            }
            {
                unsigned kk = keys[j].w;
                if (kk > T) o.w = valOf(kk);
                else if (kk == T) { o.w = (r < need) ? valOf(kk) : 0.0f; ++r; }
                else o.w = 0.0f;
            }
            outRow[t + BLOCK * j] = o;
            __syncthreads();
            if (t == BLOCK - 1) sBase += run;   // run == total ties this j
        }
    }
}

extern "C" void kernel_launch(void* const* d_in, const int* in_sizes, int n_in,
                              void* d_out, int out_size, void* d_ws, size_t ws_size,
                              hipStream_t stream) {
    const float* in = (const float*)d_in[0];
    const int* kptr = (const int*)d_in[1];
    float* out = (float*)d_out;
    const int N = in_sizes[0] / ROW_D;   // 8192 rows
    TopKActivation_68324339745162_kernel<<<dim3(N), dim3(BLOCK), 0, stream>>>(in, out, kptr);
}